// Round 8
// baseline (235.824 us; speedup 1.0000x reference)
//
#include <hip/hip_runtime.h>
#include <hip/hip_bf16.h>

#define Bb 128
#define Tt 1024
#define Ff 128
#define Kk 32
#define KS 40          // S LDS row stride (bf16): 80 B rows -> b128-aligned frags
#define KE 36          // g LDS row stride (floats)
#define LOG32 3.4657359027997265f

typedef __attribute__((ext_vector_type(8))) short bf16x8;
typedef __attribute__((ext_vector_type(4))) float f32x4;

__device__ __forceinline__ float bf2f(unsigned u) {
    return __uint_as_float(u << 16);
}
__device__ __forceinline__ unsigned short f2bf(float f) {
    unsigned u = __float_as_uint(f);
    u = (u + 0x7fffu + ((u >> 16) & 1u)) >> 16;      // RNE
    return (unsigned short)u;
}
// packed f32x2 -> bf16x2 (v_cvt_pk_bf16_f32 on gfx950 via HIP header)
__device__ __forceinline__ unsigned bfpk2(float a, float b) {
    __hip_bfloat162 h = __float22bfloat162_rn(make_float2(a, b));
    unsigned u;
    __builtin_memcpy(&u, &h, sizeof(u));
    return u;
}

// ---------------------------------------------------------------------------
// Fused kernel: per (batch, chunk) block:
//   1. emission tile em[t0..t0+31][0..31] via 16 MFMAs; g = exp(em-log32) in LDS
//   2. S_c = Q_c^T chain: S <- diag(g_t) * (E^T * S) over unmasked steps
//   3. write S_c to SQ; last-arriving block of batch b runs the serial
//      32-chunk apply (readlane matvec) and atomicAdds log_z into out.
// ---------------------------------------------------------------------------
__global__ __launch_bounds__(64, 4) void crf_kernel(
    const float* __restrict__ inp, const int* __restrict__ mask,
    const float* __restrict__ W, const float* __restrict__ trans,
    unsigned short* __restrict__ SQ, int* __restrict__ cnt,
    float* __restrict__ out)
{
    __shared__ __align__(16) float gl[32 * KE];
    __shared__ __align__(16) unsigned short Sl[32 * KS];
    const int lane = threadIdx.x & 63;
    const int q = lane >> 4, n = lane & 15;
    const int b = blockIdx.x >> 5, c = blockIdx.x & 31;
    const int t0 = c ? c * 32 : 1;
    const int L  = c ? 32 : 31;

    // chunk mask -> wave-uniform bitmask
    const int* mbp = mask + (long)b * Tt;
    int mybit = (lane < L) ? (mbp[t0 + lane] != 0) : 0;
    const unsigned mbits = (unsigned)__ballot(mybit);

    // Fixed A-operand: A_i[j] = E^T[i*16+n][q*8+j]
    bf16x8 A0, A1;
    #pragma unroll
    for (int j = 0; j < 8; ++j) {
        A0[j] = (short)f2bf(__expf(trans[(q * 8 + j) * Kk + n]));
        A1[j] = (short)f2bf(__expf(trans[(q * 8 + j) * Kk + 16 + n]));
    }

    // ---- emission tile via MFMA ----
    const f32x4 zz = {0.f, 0.f, 0.f, 0.f};
    f32x4 E00 = zz, E01 = zz, E10 = zz, E11 = zz;
    const float* xrow = inp + ((long)b * Tt + t0) * Ff;
    #pragma unroll
    for (int kt = 0; kt < 4; ++kt) {
        const int f0 = kt * 32 + q * 8;
        float4 al0 = *(const float4*)&xrow[ n        * Ff + f0];
        float4 al1 = *(const float4*)&xrow[ n        * Ff + f0 + 4];
        float4 ah0 = *(const float4*)&xrow[(n + 16)  * Ff + f0];
        float4 ah1 = *(const float4*)&xrow[(n + 16)  * Ff + f0 + 4];
        uint4 ua = make_uint4(bfpk2(al0.x, al0.y), bfpk2(al0.z, al0.w),
                              bfpk2(al1.x, al1.y), bfpk2(al1.z, al1.w));
        uint4 ub = make_uint4(bfpk2(ah0.x, ah0.y), bfpk2(ah0.z, ah0.w),
                              bfpk2(ah1.x, ah1.y), bfpk2(ah1.z, ah1.w));
        bf16x8 Alo, Ahi;
        __builtin_memcpy(&Alo, &ua, 16);
        __builtin_memcpy(&Ahi, &ub, 16);
        float wl[8], wh[8];
        #pragma unroll
        for (int jj = 0; jj < 8; ++jj) {
            wl[jj] = W[(f0 + jj) * Kk + n];
            wh[jj] = W[(f0 + jj) * Kk + 16 + n];
        }
        uint4 uc = make_uint4(bfpk2(wl[0], wl[1]), bfpk2(wl[2], wl[3]),
                              bfpk2(wl[4], wl[5]), bfpk2(wl[6], wl[7]));
        uint4 ud = make_uint4(bfpk2(wh[0], wh[1]), bfpk2(wh[2], wh[3]),
                              bfpk2(wh[4], wh[5]), bfpk2(wh[6], wh[7]));
        bf16x8 Blo, Bhi;
        __builtin_memcpy(&Blo, &uc, 16);
        __builtin_memcpy(&Bhi, &ud, 16);
        E00 = __builtin_amdgcn_mfma_f32_16x16x32_bf16(Alo, Blo, E00, 0, 0, 0);
        E01 = __builtin_amdgcn_mfma_f32_16x16x32_bf16(Alo, Bhi, E01, 0, 0, 0);
        E10 = __builtin_amdgcn_mfma_f32_16x16x32_bf16(Ahi, Blo, E10, 0, 0, 0);
        E11 = __builtin_amdgcn_mfma_f32_16x16x32_bf16(Ahi, Bhi, E11, 0, 0, 0);
    }
    #pragma unroll
    for (int r = 0; r < 4; ++r) {
        gl[( q * 4 + r)      * KE + n]      = __expf(E00[r] - LOG32);
        gl[( q * 4 + r)      * KE + 16 + n] = __expf(E01[r] - LOG32);
        gl[(16 + q * 4 + r)  * KE + n]      = __expf(E10[r] - LOG32);
        gl[(16 + q * 4 + r)  * KE + 16 + n] = __expf(E11[r] - LOG32);
    }

    // ---- S = I (column-major bf16, stride KS) ----
    for (int i = lane; i < (32 * KS) / 2; i += 64)
        ((unsigned*)Sl)[i] = 0u;
    if (lane < 32) Sl[lane * KS + lane] = 0x3f80;

    for (int s = 0; s < L; ++s) {
        if (!((mbits >> s) & 1u)) continue;
        // B-frags: 8 contiguous bf16 at Sl[row*KS + q*8] -> one b128 each
        uint4 u0 = *(const uint4*)&Sl[ n       * KS + q * 8];
        uint4 u1 = *(const uint4*)&Sl[(n + 16) * KS + q * 8];
        bf16x8 B0, B1;
        __builtin_memcpy(&B0, &u0, 16);
        __builtin_memcpy(&B1, &u1, 16);
        f32x4 D00 = __builtin_amdgcn_mfma_f32_16x16x32_bf16(A0, B0, zz, 0, 0, 0);
        f32x4 D01 = __builtin_amdgcn_mfma_f32_16x16x32_bf16(A0, B1, zz, 0, 0, 0);
        f32x4 D10 = __builtin_amdgcn_mfma_f32_16x16x32_bf16(A1, B0, zz, 0, 0, 0);
        f32x4 D11 = __builtin_amdgcn_mfma_f32_16x16x32_bf16(A1, B1, zz, 0, 0, 0);
        float4 g0 = *(const float4*)&gl[s * KE + q * 4];
        float4 g1 = *(const float4*)&gl[s * KE + 16 + q * 4];
        *(uint2*)&Sl[ n       * KS      + q * 4] =
            make_uint2(bfpk2(D00[0] * g0.x, D00[1] * g0.y), bfpk2(D00[2] * g0.z, D00[3] * g0.w));
        *(uint2*)&Sl[(n + 16) * KS      + q * 4] =
            make_uint2(bfpk2(D01[0] * g0.x, D01[1] * g0.y), bfpk2(D01[2] * g0.z, D01[3] * g0.w));
        *(uint2*)&Sl[ n       * KS + 16 + q * 4] =
            make_uint2(bfpk2(D10[0] * g1.x, D10[1] * g1.y), bfpk2(D10[2] * g1.z, D10[3] * g1.w));
        *(uint2*)&Sl[(n + 16) * KS + 16 + q * 4] =
            make_uint2(bfpk2(D11[0] * g1.x, D11[1] * g1.y), bfpk2(D11[2] * g1.z, D11[3] * g1.w));
    }

    // Write S row-major to global: sq[k*32 + n] = S[k][n]
    unsigned short* sq = SQ + (long)(b * 32 + c) * 1024;
    #pragma unroll
    for (int it = 0; it < 2; ++it) {
        int f = it * 512 + lane * 8;
        int kk = f >> 5, n0 = f & 31;
        unsigned v[4];
        #pragma unroll
        for (int e = 0; e < 4; ++e) {
            unsigned lo = Sl[(n0 + 2 * e    ) * KS + kk];
            unsigned hi = Sl[(n0 + 2 * e + 1) * KS + kk];
            v[e] = lo | (hi << 16);
        }
        *(uint4*)(sq + f) = make_uint4(v[0], v[1], v[2], v[3]);
    }

    // ---- last-arrival collection ----
    __threadfence();                          // release SQ writes (device scope)
    int old = 0;
    if (lane == 0) old = atomicAdd(&cnt[b], 1);
    old = __shfl(old, 0);
    if (old != 31) return;
    __threadfence();                          // acquire others' SQ writes

    // ===== apply phase for batch b (verified readlane matvec) =====
    const int k = lane & 31;
    const unsigned short* sqb = SQ + (long)b * 32 * 1024;
    uint4 cur[4], nxt[4];
    #pragma unroll
    for (int e = 0; e < 4; ++e) cur[e] = *(const uint4*)(sqb + k * 32 + 8 * e);
    #pragma unroll
    for (int e = 0; e < 4; ++e) nxt[e] = *(const uint4*)(sqb + 1024 + k * 32 + 8 * e);

    // applied-step count (t = 1..1023, mask != 0)
    int cc = 0;
    #pragma unroll
    for (int it = 0; it < 16; ++it) cc += (mbp[it * 64 + lane] != 0) ? 1 : 0;
    #pragma unroll
    for (int off = 32; off; off >>= 1) cc += __shfl_xor(cc, off);
    cc -= (mbp[0] != 0) ? 1 : 0;

    // alpha0[k] = dot(inp[b,0,:], W[:,k]) in fp32
    const float* x0 = inp + (long)b * Tt * Ff;
    float a0 = 0.f;
    #pragma unroll 4
    for (int f = 0; f < Ff; ++f)
        a0 = fmaf(x0[f], W[f * Kk + k], a0);

    float c0 = __int_as_float(__builtin_amdgcn_readlane(__float_as_int(a0), 0));
    float p = __expf(a0 - c0);
    float csum = c0 + (float)cc * LOG32;

    for (int ci = 0; ci < 32; ++ci) {
        uint4 pf[4];
        if (ci + 2 < 32) {
            const unsigned short* s2 = sqb + (ci + 2) * 1024 + k * 32;
            #pragma unroll
            for (int e = 0; e < 4; ++e) pf[e] = *(const uint4*)(s2 + 8 * e);
        }
        const int pi = __float_as_int(p);
        float q0 = 0.f, q1 = 0.f, q2 = 0.f, q3 = 0.f;
        #define RL(j) __int_as_float(__builtin_amdgcn_readlane(pi, (j)))
        #define ACC2(word, j, acc) \
            acc = fmaf(bf2f((word) & 0xffffu), RL(j), acc); \
            acc = fmaf(bf2f((word) >> 16),     RL((j) + 1), acc);
        ACC2(cur[0].x,  0, q0) ACC2(cur[0].y,  2, q0) ACC2(cur[0].z,  4, q0) ACC2(cur[0].w,  6, q0)
        ACC2(cur[1].x,  8, q1) ACC2(cur[1].y, 10, q1) ACC2(cur[1].z, 12, q1) ACC2(cur[1].w, 14, q1)
        ACC2(cur[2].x, 16, q2) ACC2(cur[2].y, 18, q2) ACC2(cur[2].z, 20, q2) ACC2(cur[2].w, 22, q2)
        ACC2(cur[3].x, 24, q3) ACC2(cur[3].y, 26, q3) ACC2(cur[3].z, 28, q3) ACC2(cur[3].w, 30, q3)
        #undef ACC2
        #undef RL
        float qq = (q0 + q1) + (q2 + q3);
        if (ci == 15) {     // single mid-point rescale
            float s0 = __int_as_float(__builtin_amdgcn_readlane(__float_as_int(qq), 0));
            csum += __logf(s0);
            qq *= (1.0f / s0);
        }
        p = qq;
        #pragma unroll
        for (int e = 0; e < 4; ++e) { cur[e] = nxt[e]; nxt[e] = pf[e]; }
    }

    float sum = p;
    #pragma unroll
    for (int off = 16; off > 0; off >>= 1)
        sum += __shfl_xor(sum, off);
    if (lane == 0)
        atomicAdd(out, csum + __logf(sum));
}

extern "C" void kernel_launch(void* const* d_in, const int* in_sizes, int n_in,
                              void* d_out, int out_size, void* d_ws, size_t ws_size,
                              hipStream_t stream)
{
    const float* inp   = (const float*)d_in[0];
    const int*   mask  = (const int*)d_in[1];
    const float* W     = (const float*)d_in[2];
    const float* trans = (const float*)d_in[3];
    float* out = (float*)d_out;
    const size_t sq_bytes = (size_t)Bb * 32 * 1024 * 2;       // 8 MB
    unsigned short* SQ = (unsigned short*)d_ws;
    int* cnt = (int*)((char*)d_ws + sq_bytes);                // 128 ints

    (void)hipMemsetAsync(d_out, 0, sizeof(float), stream);
    (void)hipMemsetAsync(cnt, 0, Bb * sizeof(int), stream);
    crf_kernel<<<dim3(Bb * 32), dim3(64), 0, stream>>>(inp, mask, W, trans, SQ, cnt, out);
}

// Round 9
// 130.826 us; speedup vs baseline: 1.8026x; 1.8026x over previous
//
#include <hip/hip_runtime.h>
#include <hip/hip_bf16.h>

#define Bb 128
#define Tt 1024
#define Ff 128
#define Kk 32
#define KS 36          // S LDS row stride (bf16 elems): 72 B, divisible by 8
#define KE 36          // g LDS row stride (floats)
#define LOG32 3.4657359027997265f

typedef __attribute__((ext_vector_type(8))) short bf16x8;
typedef __attribute__((ext_vector_type(4))) float f32x4;

__device__ __forceinline__ float bf2f(unsigned u) {
    return __uint_as_float(u << 16);
}
__device__ __forceinline__ unsigned short f2bf(float f) {
    unsigned u = __float_as_uint(f);
    u = (u + 0x7fffu + ((u >> 16) & 1u)) >> 16;      // RNE
    return (unsigned short)u;
}
// packed f32x2 -> bf16x2 (v_cvt_pk_bf16_f32 on gfx950)
__device__ __forceinline__ unsigned bfpk2(float a, float b) {
    __hip_bfloat162 h = __float22bfloat162_rn(make_float2(a, b));
    unsigned u;
    __builtin_memcpy(&u, &h, sizeof(u));
    return u;
}

// ---------------------------------------------------------------------------
// Kernel 1 (phase A, fused emission): per (batch, chunk):
//   1. emission tile em[t0..t0+31][0..31] via 16 MFMAs; g = exp(em-log32) in LDS
//   2. S_c = Q_c^T chain: S <- diag(g_t) * (E^T * S) over unmasked steps
//      (mask preloaded to a wave-uniform bitmask)
//   3. write S_c row-major to SQ.
// One wave per block. E^T is the fixed MFMA A-operand.
// ---------------------------------------------------------------------------
__global__ __launch_bounds__(64, 4) void chunk_kernel(
    const float* __restrict__ inp, const int* __restrict__ mask,
    const float* __restrict__ W, const float* __restrict__ trans,
    unsigned short* __restrict__ SQ)
{
    __shared__ __align__(16) float gl[32 * KE];
    __shared__ __align__(16) unsigned short Sl[32 * KS];
    const int lane = threadIdx.x & 63;
    const int q = lane >> 4, n = lane & 15;
    const int b = blockIdx.x >> 5, c = blockIdx.x & 31;
    const int t0 = c ? c * 32 : 1;
    const int L  = c ? 32 : 31;

    // chunk mask -> wave-uniform bitmask
    const int* mbp = mask + (long)b * Tt;
    int mybit = (lane < L) ? (mbp[t0 + lane] != 0) : 0;
    const unsigned mbits = (unsigned)__ballot(mybit);

    // Fixed A-operand: A_i[j] = E^T[i*16+n][q*8+j]
    bf16x8 A0, A1;
    #pragma unroll
    for (int j = 0; j < 8; ++j) {
        A0[j] = (short)f2bf(__expf(trans[(q * 8 + j) * Kk + n]));
        A1[j] = (short)f2bf(__expf(trans[(q * 8 + j) * Kk + 16 + n]));
    }

    // ---- emission tile via MFMA ----
    const f32x4 zz = {0.f, 0.f, 0.f, 0.f};
    f32x4 E00 = zz, E01 = zz, E10 = zz, E11 = zz;
    const float* xrow = inp + ((long)b * Tt + t0) * Ff;
    #pragma unroll
    for (int kt = 0; kt < 4; ++kt) {
        const int f0 = kt * 32 + q * 8;
        float4 al0 = *(const float4*)&xrow[ n        * Ff + f0];
        float4 al1 = *(const float4*)&xrow[ n        * Ff + f0 + 4];
        float4 ah0 = *(const float4*)&xrow[(n + 16)  * Ff + f0];
        float4 ah1 = *(const float4*)&xrow[(n + 16)  * Ff + f0 + 4];
        uint4 ua = make_uint4(bfpk2(al0.x, al0.y), bfpk2(al0.z, al0.w),
                              bfpk2(al1.x, al1.y), bfpk2(al1.z, al1.w));
        uint4 ub = make_uint4(bfpk2(ah0.x, ah0.y), bfpk2(ah0.z, ah0.w),
                              bfpk2(ah1.x, ah1.y), bfpk2(ah1.z, ah1.w));
        bf16x8 Alo = __builtin_bit_cast(bf16x8, ua);
        bf16x8 Ahi = __builtin_bit_cast(bf16x8, ub);
        float wl[8], wh[8];
        #pragma unroll
        for (int jj = 0; jj < 8; ++jj) {
            wl[jj] = W[(f0 + jj) * Kk + n];
            wh[jj] = W[(f0 + jj) * Kk + 16 + n];
        }
        uint4 uc = make_uint4(bfpk2(wl[0], wl[1]), bfpk2(wl[2], wl[3]),
                              bfpk2(wl[4], wl[5]), bfpk2(wl[6], wl[7]));
        uint4 ud = make_uint4(bfpk2(wh[0], wh[1]), bfpk2(wh[2], wh[3]),
                              bfpk2(wh[4], wh[5]), bfpk2(wh[6], wh[7]));
        bf16x8 Blo = __builtin_bit_cast(bf16x8, uc);
        bf16x8 Bhi = __builtin_bit_cast(bf16x8, ud);
        E00 = __builtin_amdgcn_mfma_f32_16x16x32_bf16(Alo, Blo, E00, 0, 0, 0);
        E01 = __builtin_amdgcn_mfma_f32_16x16x32_bf16(Alo, Bhi, E01, 0, 0, 0);
        E10 = __builtin_amdgcn_mfma_f32_16x16x32_bf16(Ahi, Blo, E10, 0, 0, 0);
        E11 = __builtin_amdgcn_mfma_f32_16x16x32_bf16(Ahi, Bhi, E11, 0, 0, 0);
    }
    #pragma unroll
    for (int r = 0; r < 4; ++r) {
        gl[( q * 4 + r)      * KE + n]      = __expf(E00[r] - LOG32);
        gl[( q * 4 + r)      * KE + 16 + n] = __expf(E01[r] - LOG32);
        gl[(16 + q * 4 + r)  * KE + n]      = __expf(E10[r] - LOG32);
        gl[(16 + q * 4 + r)  * KE + 16 + n] = __expf(E11[r] - LOG32);
    }

    // ---- S = I (column-major bf16, stride KS) ----
    for (int i = lane; i < (32 * KS) / 2; i += 64)
        ((unsigned*)Sl)[i] = 0u;
    if (lane < 32) Sl[lane * KS + lane] = 0x3f80;

    for (int s = 0; s < L; ++s) {
        if (!((mbits >> s) & 1u)) continue;       // masked: S unchanged (SALU)
        // B-frags: B_j[k][n] = S[k][j*16+n] = Sl[(j*16+n)*KS + k], k = q*8+jj
        uint2 xa = *(const uint2*)&Sl[ n       * KS + q * 8];
        uint2 xb = *(const uint2*)&Sl[ n       * KS + q * 8 + 4];
        uint2 ya = *(const uint2*)&Sl[(n + 16) * KS + q * 8];
        uint2 yb = *(const uint2*)&Sl[(n + 16) * KS + q * 8 + 4];
        uint4 u0 = make_uint4(xa.x, xa.y, xb.x, xb.y);
        uint4 u1 = make_uint4(ya.x, ya.y, yb.x, yb.y);
        bf16x8 B0 = __builtin_bit_cast(bf16x8, u0);
        bf16x8 B1 = __builtin_bit_cast(bf16x8, u1);
        f32x4 D00 = __builtin_amdgcn_mfma_f32_16x16x32_bf16(A0, B0, zz, 0, 0, 0);
        f32x4 D01 = __builtin_amdgcn_mfma_f32_16x16x32_bf16(A0, B1, zz, 0, 0, 0);
        f32x4 D10 = __builtin_amdgcn_mfma_f32_16x16x32_bf16(A1, B0, zz, 0, 0, 0);
        f32x4 D11 = __builtin_amdgcn_mfma_f32_16x16x32_bf16(A1, B1, zz, 0, 0, 0);
        float4 g0 = *(const float4*)&gl[s * KE + q * 4];
        float4 g1 = *(const float4*)&gl[s * KE + 16 + q * 4];
        *(uint2*)&Sl[ n       * KS      + q * 4] =
            make_uint2(bfpk2(D00[0] * g0.x, D00[1] * g0.y), bfpk2(D00[2] * g0.z, D00[3] * g0.w));
        *(uint2*)&Sl[(n + 16) * KS      + q * 4] =
            make_uint2(bfpk2(D01[0] * g0.x, D01[1] * g0.y), bfpk2(D01[2] * g0.z, D01[3] * g0.w));
        *(uint2*)&Sl[ n       * KS + 16 + q * 4] =
            make_uint2(bfpk2(D10[0] * g1.x, D10[1] * g1.y), bfpk2(D10[2] * g1.z, D10[3] * g1.w));
        *(uint2*)&Sl[(n + 16) * KS + 16 + q * 4] =
            make_uint2(bfpk2(D11[0] * g1.x, D11[1] * g1.y), bfpk2(D11[2] * g1.z, D11[3] * g1.w));
    }

    // Write S row-major to global: sq[k*32 + n] = S[k][n]
    unsigned short* sq = SQ + (long)(b * 32 + c) * 1024;
    #pragma unroll
    for (int it = 0; it < 2; ++it) {
        int f = it * 512 + lane * 8;
        int kk = f >> 5, n0 = f & 31;
        unsigned v[4];
        #pragma unroll
        for (int e = 0; e < 4; ++e) {
            unsigned lo = Sl[(n0 + 2 * e    ) * KS + kk];
            unsigned hi = Sl[(n0 + 2 * e + 1) * KS + kk];
            v[e] = lo | (hi << 16);
        }
        *(uint4*)(sq + f) = make_uint4(v[0], v[1], v[2], v[3]);
    }
}

// ---------------------------------------------------------------------------
// Kernel 2 (phase B): per batch, p^T <- p^T Q_c for c = 0..31.
// Two-deep prefetch; single mid-point rescale (drift stays inside fp32).
// ---------------------------------------------------------------------------
__global__ __launch_bounds__(64) void apply_kernel(
    const float* __restrict__ inp, const int* __restrict__ mask,
    const float* __restrict__ W, const unsigned short* __restrict__ SQ,
    float* __restrict__ out)
{
    const int b = blockIdx.x, lane = threadIdx.x & 63, k = lane & 31;
    const int* mbp = mask + (long)b * Tt;

    const unsigned short* sqb = SQ + (long)b * 32 * 1024;
    uint4 cur[4], nxt[4];
    #pragma unroll
    for (int e = 0; e < 4; ++e) cur[e] = *(const uint4*)(sqb + k * 32 + 8 * e);
    #pragma unroll
    for (int e = 0; e < 4; ++e) nxt[e] = *(const uint4*)(sqb + 1024 + k * 32 + 8 * e);

    // count applied steps (t = 1..1023 with mask != 0)
    int cnt = 0;
    #pragma unroll
    for (int it = 0; it < 16; ++it) cnt += (mbp[it * 64 + lane] != 0) ? 1 : 0;
    #pragma unroll
    for (int off = 32; off; off >>= 1) cnt += __shfl_xor(cnt, off);
    cnt -= (mbp[0] != 0) ? 1 : 0;

    // alpha0[k] = dot(inp[b,0,:], W[:,k]) in fp32
    const float* x0 = inp + (long)b * Tt * Ff;
    float a0 = 0.f;
    #pragma unroll 4
    for (int f = 0; f < Ff; ++f)
        a0 = fmaf(x0[f], W[f * Kk + k], a0);

    float c0 = __int_as_float(__builtin_amdgcn_readlane(__float_as_int(a0), 0));
    float p = __expf(a0 - c0);
    float csum = c0 + (float)cnt * LOG32;

    for (int c = 0; c < 32; ++c) {
        uint4 pf[4];
        if (c + 2 < 32) {
            const unsigned short* s2 = sqb + (c + 2) * 1024 + k * 32;
            #pragma unroll
            for (int e = 0; e < 4; ++e) pf[e] = *(const uint4*)(s2 + 8 * e);
        }
        const int pi = __float_as_int(p);
        float q0 = 0.f, q1 = 0.f, q2 = 0.f, q3 = 0.f;
        #define RL(j) __int_as_float(__builtin_amdgcn_readlane(pi, (j)))
        #define ACC2(word, j, acc) \
            acc = fmaf(bf2f((word) & 0xffffu), RL(j), acc); \
            acc = fmaf(bf2f((word) >> 16),     RL((j) + 1), acc);
        ACC2(cur[0].x,  0, q0) ACC2(cur[0].y,  2, q0) ACC2(cur[0].z,  4, q0) ACC2(cur[0].w,  6, q0)
        ACC2(cur[1].x,  8, q1) ACC2(cur[1].y, 10, q1) ACC2(cur[1].z, 12, q1) ACC2(cur[1].w, 14, q1)
        ACC2(cur[2].x, 16, q2) ACC2(cur[2].y, 18, q2) ACC2(cur[2].z, 20, q2) ACC2(cur[2].w, 22, q2)
        ACC2(cur[3].x, 24, q3) ACC2(cur[3].y, 26, q3) ACC2(cur[3].z, 28, q3) ACC2(cur[3].w, 30, q3)
        #undef ACC2
        #undef RL
        float qq = (q0 + q1) + (q2 + q3);
        if (c == 15) {   // single mid-point rescale keeps p well inside fp32
            float s0 = __int_as_float(__builtin_amdgcn_readlane(__float_as_int(qq), 0));
            csum += __logf(s0);
            qq *= (1.0f / s0);
        }
        p = qq;
        #pragma unroll
        for (int e = 0; e < 4; ++e) { cur[e] = nxt[e]; nxt[e] = pf[e]; }
    }

    float sum = p;
    #pragma unroll
    for (int off = 16; off > 0; off >>= 1)
        sum += __shfl_xor(sum, off);
    if (lane == 0)
        atomicAdd(out, csum + __logf(sum));
}

extern "C" void kernel_launch(void* const* d_in, const int* in_sizes, int n_in,
                              void* d_out, int out_size, void* d_ws, size_t ws_size,
                              hipStream_t stream)
{
    const float* inp   = (const float*)d_in[0];
    const int*   mask  = (const int*)d_in[1];
    const float* W     = (const float*)d_in[2];
    const float* trans = (const float*)d_in[3];
    float* out = (float*)d_out;
    unsigned short* SQ = (unsigned short*)d_ws;   // 128*32 chunk matrices * 2 KB = 8 MB

    (void)hipMemsetAsync(d_out, 0, sizeof(float), stream);
    chunk_kernel<<<dim3(Bb * 32), dim3(64), 0, stream>>>(inp, mask, W, trans, SQ);
    apply_kernel<<<dim3(Bb), dim3(64), 0, stream>>>(inp, mask, W, SQ, out);
}

// Round 10
// 128.552 us; speedup vs baseline: 1.8345x; 1.0177x over previous
//
#include <hip/hip_runtime.h>
#include <hip/hip_bf16.h>

#define Bb 128
#define Tt 1024
#define Ff 128
#define Kk 32
#define KS 36          // S LDS row stride (bf16 elems): 72 B, divisible by 8
#define KE 36          // g LDS row stride (floats)
#define LOG32 3.4657359027997265f

typedef __attribute__((ext_vector_type(8))) short bf16x8;
typedef __attribute__((ext_vector_type(4))) float f32x4;

__device__ __forceinline__ float bf2f(unsigned u) {
    return __uint_as_float(u << 16);
}
__device__ __forceinline__ unsigned short f2bf(float f) {
    unsigned u = __float_as_uint(f);
    u = (u + 0x7fffu + ((u >> 16) & 1u)) >> 16;      // RNE
    return (unsigned short)u;
}
// packed f32x2 -> bf16x2 (v_cvt_pk_bf16_f32 on gfx950)
__device__ __forceinline__ unsigned bfpk2(float a, float b) {
    __hip_bfloat162 h = __float22bfloat162_rn(make_float2(a, b));
    unsigned u;
    __builtin_memcpy(&u, &h, sizeof(u));
    return u;
}

// ---------------------------------------------------------------------------
// Kernel 1 (phase A, fused emission): per (batch, chunk):
//   1. emission tile em[c*32 .. c*32+31][0..31] via 16 MFMAs; g = exp(em-log32)
//      scattered to LDS.
//   2. S_c = Q_c^T chain: S <- diag(g_t) * (E^T * S) over unmasked steps.
//      Constant 32-trip fully-unrolled loop (chunk 0's t=0 bit is forced off:
//      t=0 is the init state, not a step). All LDS offsets become immediates.
//   3. write S_c row-major to SQ.
// One wave per block. E^T is the fixed MFMA A-operand.
// Block 0 also zeroes out[0] (replaces a memset dispatch; apply runs in a
// later kernel so no race with its atomicAdds).
// ---------------------------------------------------------------------------
__global__ __launch_bounds__(64, 4) void chunk_kernel(
    const float* __restrict__ inp, const int* __restrict__ mask,
    const float* __restrict__ W, const float* __restrict__ trans,
    unsigned short* __restrict__ SQ, float* __restrict__ out)
{
    __shared__ __align__(16) float gl[32 * KE];
    __shared__ __align__(16) unsigned short Sl[32 * KS];
    const int lane = threadIdx.x & 63;
    const int q = lane >> 4, n = lane & 15;
    const int b = blockIdx.x >> 5, c = blockIdx.x & 31;
    const int t0 = c * 32;

    if (blockIdx.x == 0 && lane == 0) out[0] = 0.f;

    // chunk mask -> wave-uniform bitmask; t=0 is init, never a step
    const int* mbp = mask + (long)b * Tt;
    int mybit = (lane < 32) ? (mbp[t0 + lane] != 0) : 0;
    unsigned mbits = (unsigned)__ballot(mybit);
    if (c == 0) mbits &= ~1u;

    // Fixed A-operand: A_i[j] = E^T[i*16+n][q*8+j]
    bf16x8 A0, A1;
    #pragma unroll
    for (int j = 0; j < 8; ++j) {
        A0[j] = (short)f2bf(__expf(trans[(q * 8 + j) * Kk + n]));
        A1[j] = (short)f2bf(__expf(trans[(q * 8 + j) * Kk + 16 + n]));
    }

    // ---- emission tile via MFMA ----
    const f32x4 zz = {0.f, 0.f, 0.f, 0.f};
    f32x4 E00 = zz, E01 = zz, E10 = zz, E11 = zz;
    const float* xrow = inp + ((long)b * Tt + t0) * Ff;
    #pragma unroll
    for (int kt = 0; kt < 4; ++kt) {
        const int f0 = kt * 32 + q * 8;
        float4 al0 = *(const float4*)&xrow[ n        * Ff + f0];
        float4 al1 = *(const float4*)&xrow[ n        * Ff + f0 + 4];
        float4 ah0 = *(const float4*)&xrow[(n + 16)  * Ff + f0];
        float4 ah1 = *(const float4*)&xrow[(n + 16)  * Ff + f0 + 4];
        uint4 ua = make_uint4(bfpk2(al0.x, al0.y), bfpk2(al0.z, al0.w),
                              bfpk2(al1.x, al1.y), bfpk2(al1.z, al1.w));
        uint4 ub = make_uint4(bfpk2(ah0.x, ah0.y), bfpk2(ah0.z, ah0.w),
                              bfpk2(ah1.x, ah1.y), bfpk2(ah1.z, ah1.w));
        bf16x8 Alo = __builtin_bit_cast(bf16x8, ua);
        bf16x8 Ahi = __builtin_bit_cast(bf16x8, ub);
        float wl[8], wh[8];
        #pragma unroll
        for (int jj = 0; jj < 8; ++jj) {
            wl[jj] = W[(f0 + jj) * Kk + n];
            wh[jj] = W[(f0 + jj) * Kk + 16 + n];
        }
        uint4 uc = make_uint4(bfpk2(wl[0], wl[1]), bfpk2(wl[2], wl[3]),
                              bfpk2(wl[4], wl[5]), bfpk2(wl[6], wl[7]));
        uint4 ud = make_uint4(bfpk2(wh[0], wh[1]), bfpk2(wh[2], wh[3]),
                              bfpk2(wh[4], wh[5]), bfpk2(wh[6], wh[7]));
        bf16x8 Blo = __builtin_bit_cast(bf16x8, uc);
        bf16x8 Bhi = __builtin_bit_cast(bf16x8, ud);
        E00 = __builtin_amdgcn_mfma_f32_16x16x32_bf16(Alo, Blo, E00, 0, 0, 0);
        E01 = __builtin_amdgcn_mfma_f32_16x16x32_bf16(Alo, Bhi, E01, 0, 0, 0);
        E10 = __builtin_amdgcn_mfma_f32_16x16x32_bf16(Ahi, Blo, E10, 0, 0, 0);
        E11 = __builtin_amdgcn_mfma_f32_16x16x32_bf16(Ahi, Bhi, E11, 0, 0, 0);
    }
    #pragma unroll
    for (int r = 0; r < 4; ++r) {
        gl[( q * 4 + r)      * KE + n]      = __expf(E00[r] - LOG32);
        gl[( q * 4 + r)      * KE + 16 + n] = __expf(E01[r] - LOG32);
        gl[(16 + q * 4 + r)  * KE + n]      = __expf(E10[r] - LOG32);
        gl[(16 + q * 4 + r)  * KE + 16 + n] = __expf(E11[r] - LOG32);
    }

    // ---- S = I (column-major bf16, stride KS) ----
    for (int i = lane; i < (32 * KS) / 2; i += 64)
        ((unsigned*)Sl)[i] = 0u;
    if (lane < 32) Sl[lane * KS + lane] = 0x3f80;

    #pragma unroll
    for (int s = 0; s < 32; ++s) {
        if (!((mbits >> s) & 1u)) continue;       // masked: S unchanged (SALU)
        // B-frags: B_j[k][n] = S[k][j*16+n] = Sl[(j*16+n)*KS + k], k = q*8+jj
        uint2 xa = *(const uint2*)&Sl[ n       * KS + q * 8];
        uint2 xb = *(const uint2*)&Sl[ n       * KS + q * 8 + 4];
        uint2 ya = *(const uint2*)&Sl[(n + 16) * KS + q * 8];
        uint2 yb = *(const uint2*)&Sl[(n + 16) * KS + q * 8 + 4];
        uint4 u0 = make_uint4(xa.x, xa.y, xb.x, xb.y);
        uint4 u1 = make_uint4(ya.x, ya.y, yb.x, yb.y);
        bf16x8 B0 = __builtin_bit_cast(bf16x8, u0);
        bf16x8 B1 = __builtin_bit_cast(bf16x8, u1);
        f32x4 D00 = __builtin_amdgcn_mfma_f32_16x16x32_bf16(A0, B0, zz, 0, 0, 0);
        f32x4 D01 = __builtin_amdgcn_mfma_f32_16x16x32_bf16(A0, B1, zz, 0, 0, 0);
        f32x4 D10 = __builtin_amdgcn_mfma_f32_16x16x32_bf16(A1, B0, zz, 0, 0, 0);
        f32x4 D11 = __builtin_amdgcn_mfma_f32_16x16x32_bf16(A1, B1, zz, 0, 0, 0);
        float4 g0 = *(const float4*)&gl[s * KE + q * 4];
        float4 g1 = *(const float4*)&gl[s * KE + 16 + q * 4];
        *(uint2*)&Sl[ n       * KS      + q * 4] =
            make_uint2(bfpk2(D00[0] * g0.x, D00[1] * g0.y), bfpk2(D00[2] * g0.z, D00[3] * g0.w));
        *(uint2*)&Sl[(n + 16) * KS      + q * 4] =
            make_uint2(bfpk2(D01[0] * g0.x, D01[1] * g0.y), bfpk2(D01[2] * g0.z, D01[3] * g0.w));
        *(uint2*)&Sl[ n       * KS + 16 + q * 4] =
            make_uint2(bfpk2(D10[0] * g1.x, D10[1] * g1.y), bfpk2(D10[2] * g1.z, D10[3] * g1.w));
        *(uint2*)&Sl[(n + 16) * KS + 16 + q * 4] =
            make_uint2(bfpk2(D11[0] * g1.x, D11[1] * g1.y), bfpk2(D11[2] * g1.z, D11[3] * g1.w));
    }

    // Write S row-major to global: sq[k*32 + n] = S[k][n]
    unsigned short* sq = SQ + (long)(b * 32 + c) * 1024;
    #pragma unroll
    for (int it = 0; it < 2; ++it) {
        int f = it * 512 + lane * 8;
        int kk = f >> 5, n0 = f & 31;
        unsigned v[4];
        #pragma unroll
        for (int e = 0; e < 4; ++e) {
            unsigned lo = Sl[(n0 + 2 * e    ) * KS + kk];
            unsigned hi = Sl[(n0 + 2 * e + 1) * KS + kk];
            v[e] = lo | (hi << 16);
        }
        *(uint4*)(sq + f) = make_uint4(v[0], v[1], v[2], v[3]);
    }
}

// ---------------------------------------------------------------------------
// Kernel 2 (phase B): per batch, p^T <- p^T Q_c for c = 0..31.
// Two-deep prefetch; single mid-point rescale (drift stays inside fp32).
// ---------------------------------------------------------------------------
__global__ __launch_bounds__(64) void apply_kernel(
    const float* __restrict__ inp, const int* __restrict__ mask,
    const float* __restrict__ W, const unsigned short* __restrict__ SQ,
    float* __restrict__ out)
{
    const int b = blockIdx.x, lane = threadIdx.x & 63, k = lane & 31;
    const int* mbp = mask + (long)b * Tt;

    const unsigned short* sqb = SQ + (long)b * 32 * 1024;
    uint4 cur[4], nxt[4];
    #pragma unroll
    for (int e = 0; e < 4; ++e) cur[e] = *(const uint4*)(sqb + k * 32 + 8 * e);
    #pragma unroll
    for (int e = 0; e < 4; ++e) nxt[e] = *(const uint4*)(sqb + 1024 + k * 32 + 8 * e);

    // count applied steps (t = 1..1023 with mask != 0)
    int cnt = 0;
    #pragma unroll
    for (int it = 0; it < 16; ++it) cnt += (mbp[it * 64 + lane] != 0) ? 1 : 0;
    #pragma unroll
    for (int off = 32; off; off >>= 1) cnt += __shfl_xor(cnt, off);
    cnt -= (mbp[0] != 0) ? 1 : 0;

    // alpha0[k] = dot(inp[b,0,:], W[:,k]) in fp32
    const float* x0 = inp + (long)b * Tt * Ff;
    float a0 = 0.f;
    #pragma unroll 4
    for (int f = 0; f < Ff; ++f)
        a0 = fmaf(x0[f], W[f * Kk + k], a0);

    float c0 = __int_as_float(__builtin_amdgcn_readlane(__float_as_int(a0), 0));
    float p = __expf(a0 - c0);
    float csum = c0 + (float)cnt * LOG32;

    #pragma unroll 2
    for (int c = 0; c < 32; ++c) {
        uint4 pf[4];
        if (c + 2 < 32) {
            const unsigned short* s2 = sqb + (c + 2) * 1024 + k * 32;
            #pragma unroll
            for (int e = 0; e < 4; ++e) pf[e] = *(const uint4*)(s2 + 8 * e);
        }
        const int pi = __float_as_int(p);
        float q0 = 0.f, q1 = 0.f, q2 = 0.f, q3 = 0.f;
        #define RL(j) __int_as_float(__builtin_amdgcn_readlane(pi, (j)))
        #define ACC2(word, j, acc) \
            acc = fmaf(bf2f((word) & 0xffffu), RL(j), acc); \
            acc = fmaf(bf2f((word) >> 16),     RL((j) + 1), acc);
        ACC2(cur[0].x,  0, q0) ACC2(cur[0].y,  2, q0) ACC2(cur[0].z,  4, q0) ACC2(cur[0].w,  6, q0)
        ACC2(cur[1].x,  8, q1) ACC2(cur[1].y, 10, q1) ACC2(cur[1].z, 12, q1) ACC2(cur[1].w, 14, q1)
        ACC2(cur[2].x, 16, q2) ACC2(cur[2].y, 18, q2) ACC2(cur[2].z, 20, q2) ACC2(cur[2].w, 22, q2)
        ACC2(cur[3].x, 24, q3) ACC2(cur[3].y, 26, q3) ACC2(cur[3].z, 28, q3) ACC2(cur[3].w, 30, q3)
        #undef ACC2
        #undef RL
        float qq = (q0 + q1) + (q2 + q3);
        if (c == 15) {   // single mid-point rescale keeps p well inside fp32
            float s0 = __int_as_float(__builtin_amdgcn_readlane(__float_as_int(qq), 0));
            csum += __logf(s0);
            qq *= (1.0f / s0);
        }
        p = qq;
        #pragma unroll
        for (int e = 0; e < 4; ++e) { cur[e] = nxt[e]; nxt[e] = pf[e]; }
    }

    float sum = p;
    #pragma unroll
    for (int off = 16; off > 0; off >>= 1)
        sum += __shfl_xor(sum, off);
    if (lane == 0)
        atomicAdd(out, csum + __logf(sum));
}

extern "C" void kernel_launch(void* const* d_in, const int* in_sizes, int n_in,
                              void* d_out, int out_size, void* d_ws, size_t ws_size,
                              hipStream_t stream)
{
    const float* inp   = (const float*)d_in[0];
    const int*   mask  = (const int*)d_in[1];
    const float* W     = (const float*)d_in[2];
    const float* trans = (const float*)d_in[3];
    float* out = (float*)d_out;
    unsigned short* SQ = (unsigned short*)d_ws;   // 128*32 chunk matrices * 2 KB = 8 MB

    chunk_kernel<<<dim3(Bb * 32), dim3(64), 0, stream>>>(inp, mask, W, trans, SQ, out);
    apply_kernel<<<dim3(Bb), dim3(64), 0, stream>>>(inp, mask, W, SQ, out);
}

// Round 11
// 127.489 us; speedup vs baseline: 1.8498x; 1.0083x over previous
//
#include <hip/hip_runtime.h>
#include <hip/hip_bf16.h>

#define Bb 128
#define Tt 1024
#define Ff 128
#define Kk 32
#define KS 36          // S LDS row stride (bf16 elems): 72 B, divisible by 8
#define KE 36          // g LDS row stride (floats)
#define LOG32 3.4657359027997265f

typedef __attribute__((ext_vector_type(8))) short bf16x8;
typedef __attribute__((ext_vector_type(4))) float f32x4;

__device__ __forceinline__ float bf2f(unsigned u) {
    return __uint_as_float(u << 16);
}
__device__ __forceinline__ unsigned short f2bf(float f) {
    unsigned u = __float_as_uint(f);
    u = (u + 0x7fffu + ((u >> 16) & 1u)) >> 16;      // RNE
    return (unsigned short)u;
}
// packed f32x2 -> bf16x2 (v_cvt_pk_bf16_f32 on gfx950)
__device__ __forceinline__ unsigned bfpk2(float a, float b) {
    __hip_bfloat162 h = __float22bfloat162_rn(make_float2(a, b));
    unsigned u;
    __builtin_memcpy(&u, &h, sizeof(u));
    return u;
}

// ---------------------------------------------------------------------------
// Kernel 1: per (batch, chunk) block of 2 waves.
//   Wave w handles global steps tw = c*32 + w*16 .. tw+15:
//     emission rows tw..tw+15 via 8 MFMAs -> g = exp(em-log32) in shared gl;
//     half-chain S_w <- diag(g_t)*(E^T*S_w) over its unmasked steps (16 deep).
//   Barrier, then combine Q^T = S_b * S_a with one K=32 MFMA per tile
//   (wave w computes rows w*16..w*16+15) and store straight to SQ.
// Serial LDS-round-trip depth: 16 + 1 instead of 32.
// ---------------------------------------------------------------------------
__global__ __launch_bounds__(128, 4) void chunk_kernel(
    const float* __restrict__ inp, const int* __restrict__ mask,
    const float* __restrict__ W, const float* __restrict__ trans,
    unsigned short* __restrict__ SQ, float* __restrict__ out)
{
    __shared__ __align__(16) float gl[32 * KE];
    __shared__ __align__(16) unsigned short Sl[2][32 * KS];
    const int tid = threadIdx.x;
    const int w = tid >> 6, lane = tid & 63;
    const int q = lane >> 4, n = lane & 15;
    const int b = blockIdx.x >> 5, c = blockIdx.x & 31;
    const int tw = c * 32 + w * 16;

    if (blockIdx.x == 0 && tid == 0) out[0] = 0.f;

    // this wave's 16-step mask bits (t=0 is the init state, never a step)
    const int* mbp = mask + (long)b * Tt;
    int mybit = (lane < 16) ? (mbp[tw + lane] != 0) : 0;
    unsigned mbits = (unsigned)__ballot(mybit) & 0xffffu;
    if (c == 0 && w == 0) mbits &= ~1u;

    // Fixed A-operand for the chain: A_i[j] = E^T[i*16+n][q*8+j]
    bf16x8 A0, A1;
    #pragma unroll
    for (int j = 0; j < 8; ++j) {
        A0[j] = (short)f2bf(__expf(trans[(q * 8 + j) * Kk + n]));
        A1[j] = (short)f2bf(__expf(trans[(q * 8 + j) * Kk + 16 + n]));
    }

    // ---- emission rows tw..tw+15 via MFMA ----
    const f32x4 zz = {0.f, 0.f, 0.f, 0.f};
    f32x4 E0 = zz, E1 = zz;
    const float* xrow = inp + ((long)b * Tt + tw) * Ff;
    #pragma unroll
    for (int kt = 0; kt < 4; ++kt) {
        const int f0 = kt * 32 + q * 8;
        float4 a0v = *(const float4*)&xrow[n * Ff + f0];
        float4 a1v = *(const float4*)&xrow[n * Ff + f0 + 4];
        uint4 ua = make_uint4(bfpk2(a0v.x, a0v.y), bfpk2(a0v.z, a0v.w),
                              bfpk2(a1v.x, a1v.y), bfpk2(a1v.z, a1v.w));
        bf16x8 Aw = __builtin_bit_cast(bf16x8, ua);
        float wl[8], wh[8];
        #pragma unroll
        for (int jj = 0; jj < 8; ++jj) {
            wl[jj] = W[(f0 + jj) * Kk + n];
            wh[jj] = W[(f0 + jj) * Kk + 16 + n];
        }
        uint4 uc = make_uint4(bfpk2(wl[0], wl[1]), bfpk2(wl[2], wl[3]),
                              bfpk2(wl[4], wl[5]), bfpk2(wl[6], wl[7]));
        uint4 ud = make_uint4(bfpk2(wh[0], wh[1]), bfpk2(wh[2], wh[3]),
                              bfpk2(wh[4], wh[5]), bfpk2(wh[6], wh[7]));
        bf16x8 Blo = __builtin_bit_cast(bf16x8, uc);
        bf16x8 Bhi = __builtin_bit_cast(bf16x8, ud);
        E0 = __builtin_amdgcn_mfma_f32_16x16x32_bf16(Aw, Blo, E0, 0, 0, 0);
        E1 = __builtin_amdgcn_mfma_f32_16x16x32_bf16(Aw, Bhi, E1, 0, 0, 0);
    }
    #pragma unroll
    for (int r = 0; r < 4; ++r) {
        gl[(w * 16 + q * 4 + r) * KE + n]      = __expf(E0[r] - LOG32);
        gl[(w * 16 + q * 4 + r) * KE + 16 + n] = __expf(E1[r] - LOG32);
    }

    // ---- S_w = I (column-major bf16, stride KS) ----
    unsigned short* Sw = Sl[w];
    for (int i = lane; i < (32 * KS) / 2; i += 64)
        ((unsigned*)Sw)[i] = 0u;
    if (lane < 32) Sw[lane * KS + lane] = 0x3f80;

    #pragma unroll
    for (int ls = 0; ls < 16; ++ls) {
        if (!((mbits >> ls) & 1u)) continue;      // masked: S unchanged (SALU)
        // B-frags: B[k][col] = S[k][col] = Sw[col*KS + k], k = q*8+jj
        uint2 xa = *(const uint2*)&Sw[ n       * KS + q * 8];
        uint2 xb = *(const uint2*)&Sw[ n       * KS + q * 8 + 4];
        uint2 ya = *(const uint2*)&Sw[(n + 16) * KS + q * 8];
        uint2 yb = *(const uint2*)&Sw[(n + 16) * KS + q * 8 + 4];
        uint4 u0 = make_uint4(xa.x, xa.y, xb.x, xb.y);
        uint4 u1 = make_uint4(ya.x, ya.y, yb.x, yb.y);
        bf16x8 B0 = __builtin_bit_cast(bf16x8, u0);
        bf16x8 B1 = __builtin_bit_cast(bf16x8, u1);
        f32x4 D00 = __builtin_amdgcn_mfma_f32_16x16x32_bf16(A0, B0, zz, 0, 0, 0);
        f32x4 D01 = __builtin_amdgcn_mfma_f32_16x16x32_bf16(A0, B1, zz, 0, 0, 0);
        f32x4 D10 = __builtin_amdgcn_mfma_f32_16x16x32_bf16(A1, B0, zz, 0, 0, 0);
        f32x4 D11 = __builtin_amdgcn_mfma_f32_16x16x32_bf16(A1, B1, zz, 0, 0, 0);
        float4 g0 = *(const float4*)&gl[(w * 16 + ls) * KE + q * 4];
        float4 g1 = *(const float4*)&gl[(w * 16 + ls) * KE + 16 + q * 4];
        *(uint2*)&Sw[ n       * KS      + q * 4] =
            make_uint2(bfpk2(D00[0] * g0.x, D00[1] * g0.y), bfpk2(D00[2] * g0.z, D00[3] * g0.w));
        *(uint2*)&Sw[(n + 16) * KS      + q * 4] =
            make_uint2(bfpk2(D01[0] * g0.x, D01[1] * g0.y), bfpk2(D01[2] * g0.z, D01[3] * g0.w));
        *(uint2*)&Sw[ n       * KS + 16 + q * 4] =
            make_uint2(bfpk2(D10[0] * g1.x, D10[1] * g1.y), bfpk2(D10[2] * g1.z, D10[3] * g1.w));
        *(uint2*)&Sw[(n + 16) * KS + 16 + q * 4] =
            make_uint2(bfpk2(D11[0] * g1.x, D11[1] * g1.y), bfpk2(D11[2] * g1.z, D11[3] * g1.w));
    }

    __syncthreads();

    // ---- combine: Q^T = S_b * S_a ; wave w computes rows w*16..w*16+15 ----
    const unsigned short* SlA = Sl[0];   // S_a (steps 0..15)
    const unsigned short* SlB = Sl[1];   // S_b (steps 16..31)
    bf16x8 Af;
    #pragma unroll
    for (int j = 0; j < 8; ++j)                 // A[m][k] = S_b[w*16+n][k]
        Af[j] = (short)SlB[(q * 8 + j) * KS + w * 16 + n];
    uint2 xa = *(const uint2*)&SlA[ n       * KS + q * 8];
    uint2 xb = *(const uint2*)&SlA[ n       * KS + q * 8 + 4];
    uint2 ya = *(const uint2*)&SlA[(n + 16) * KS + q * 8];
    uint2 yb = *(const uint2*)&SlA[(n + 16) * KS + q * 8 + 4];
    uint4 u0 = make_uint4(xa.x, xa.y, xb.x, xb.y);
    uint4 u1 = make_uint4(ya.x, ya.y, yb.x, yb.y);
    bf16x8 B0 = __builtin_bit_cast(bf16x8, u0);
    bf16x8 B1 = __builtin_bit_cast(bf16x8, u1);
    f32x4 D0 = __builtin_amdgcn_mfma_f32_16x16x32_bf16(Af, B0, zz, 0, 0, 0);
    f32x4 D1 = __builtin_amdgcn_mfma_f32_16x16x32_bf16(Af, B1, zz, 0, 0, 0);

    // store straight from C-layout: sq[row*32 + col], row = w*16+q*4+r
    unsigned short* sq = SQ + (long)(b * 32 + c) * 1024;
    #pragma unroll
    for (int r = 0; r < 4; ++r) {
        sq[(w * 16 + q * 4 + r) * 32 + n]      = f2bf(D0[r]);
        sq[(w * 16 + q * 4 + r) * 32 + 16 + n] = f2bf(D1[r]);
    }
}

// ---------------------------------------------------------------------------
// Kernel 2 (phase B): per batch, p^T <- p^T Q_c for c = 0..31.
// Two-deep prefetch; single mid-point rescale (drift stays inside fp32).
// ---------------------------------------------------------------------------
__global__ __launch_bounds__(64) void apply_kernel(
    const float* __restrict__ inp, const int* __restrict__ mask,
    const float* __restrict__ W, const unsigned short* __restrict__ SQ,
    float* __restrict__ out)
{
    const int b = blockIdx.x, lane = threadIdx.x & 63, k = lane & 31;
    const int* mbp = mask + (long)b * Tt;

    const unsigned short* sqb = SQ + (long)b * 32 * 1024;
    uint4 cur[4], nxt[4];
    #pragma unroll
    for (int e = 0; e < 4; ++e) cur[e] = *(const uint4*)(sqb + k * 32 + 8 * e);
    #pragma unroll
    for (int e = 0; e < 4; ++e) nxt[e] = *(const uint4*)(sqb + 1024 + k * 32 + 8 * e);

    // count applied steps (t = 1..1023 with mask != 0)
    int cnt = 0;
    #pragma unroll
    for (int it = 0; it < 16; ++it) cnt += (mbp[it * 64 + lane] != 0) ? 1 : 0;
    #pragma unroll
    for (int off = 32; off; off >>= 1) cnt += __shfl_xor(cnt, off);
    cnt -= (mbp[0] != 0) ? 1 : 0;

    // alpha0[k] = dot(inp[b,0,:], W[:,k]) in fp32
    const float* x0 = inp + (long)b * Tt * Ff;
    float a0 = 0.f;
    #pragma unroll 4
    for (int f = 0; f < Ff; ++f)
        a0 = fmaf(x0[f], W[f * Kk + k], a0);

    float c0 = __int_as_float(__builtin_amdgcn_readlane(__float_as_int(a0), 0));
    float p = __expf(a0 - c0);
    float csum = c0 + (float)cnt * LOG32;

    #pragma unroll 2
    for (int c = 0; c < 32; ++c) {
        uint4 pf[4];
        if (c + 2 < 32) {
            const unsigned short* s2 = sqb + (c + 2) * 1024 + k * 32;
            #pragma unroll
            for (int e = 0; e < 4; ++e) pf[e] = *(const uint4*)(s2 + 8 * e);
        }
        const int pi = __float_as_int(p);
        float q0 = 0.f, q1 = 0.f, q2 = 0.f, q3 = 0.f;
        #define RL(j) __int_as_float(__builtin_amdgcn_readlane(pi, (j)))
        #define ACC2(word, j, acc) \
            acc = fmaf(bf2f((word) & 0xffffu), RL(j), acc); \
            acc = fmaf(bf2f((word) >> 16),     RL((j) + 1), acc);
        ACC2(cur[0].x,  0, q0) ACC2(cur[0].y,  2, q0) ACC2(cur[0].z,  4, q0) ACC2(cur[0].w,  6, q0)
        ACC2(cur[1].x,  8, q1) ACC2(cur[1].y, 10, q1) ACC2(cur[1].z, 12, q1) ACC2(cur[1].w, 14, q1)
        ACC2(cur[2].x, 16, q2) ACC2(cur[2].y, 18, q2) ACC2(cur[2].z, 20, q2) ACC2(cur[2].w, 22, q2)
        ACC2(cur[3].x, 24, q3) ACC2(cur[3].y, 26, q3) ACC2(cur[3].z, 28, q3) ACC2(cur[3].w, 30, q3)
        #undef ACC2
        #undef RL
        float qq = (q0 + q1) + (q2 + q3);
        if (c == 15) {   // single mid-point rescale keeps p well inside fp32
            float s0 = __int_as_float(__builtin_amdgcn_readlane(__float_as_int(qq), 0));
            csum += __logf(s0);
            qq *= (1.0f / s0);
        }
        p = qq;
        #pragma unroll
        for (int e = 0; e < 4; ++e) { cur[e] = nxt[e]; nxt[e] = pf[e]; }
    }

    float sum = p;
    #pragma unroll
    for (int off = 16; off > 0; off >>= 1)
        sum += __shfl_xor(sum, off);
    if (lane == 0)
        atomicAdd(out, csum + __logf(sum));
}

extern "C" void kernel_launch(void* const* d_in, const int* in_sizes, int n_in,
                              void* d_out, int out_size, void* d_ws, size_t ws_size,
                              hipStream_t stream)
{
    const float* inp   = (const float*)d_in[0];
    const int*   mask  = (const int*)d_in[1];
    const float* W     = (const float*)d_in[2];
    const float* trans = (const float*)d_in[3];
    float* out = (float*)d_out;
    unsigned short* SQ = (unsigned short*)d_ws;   // 128*32 chunk matrices * 2 KB = 8 MB

    chunk_kernel<<<dim3(Bb * 32), dim3(128), 0, stream>>>(inp, mask, W, trans, SQ, out);
    apply_kernel<<<dim3(Bb), dim3(64), 0, stream>>>(inp, mask, W, SQ, out);
}